// Round 4
// baseline (464.108 us; speedup 1.0000x reference)
//
#include <hip/hip_runtime.h>
#include <hip/hip_bf16.h>

#define NE 8
#define C 1024
#define F 2816

typedef __bf16 bf16_t;
typedef bf16_t bf16x8 __attribute__((ext_vector_type(8)));
typedef float f32x4 __attribute__((ext_vector_type(4)));

__device__ inline unsigned pk2(float a, float b) {
    union { bf16_t h[2]; unsigned u; } x;
    x.h[0] = (bf16_t)a; x.h[1] = (bf16_t)b;
    return x.u;
}

// async global->LDS, 16 B per lane; lds base must be wave-uniform
__device__ __forceinline__ void async_ld16(const bf16_t* g, bf16_t* l) {
    __builtin_amdgcn_global_load_lds(
        (const __attribute__((address_space(1))) unsigned int*)g,
        (__attribute__((address_space(3))) unsigned int*)l, 16, 0, 0);
}

// ---------------- router: fp32 logits, top-2, softmax; also emits bf16 x ----------------
__global__ void router_kernel(const float* __restrict__ x, const float* __restrict__ Wg,
                              float* __restrict__ probs, int* __restrict__ idxbuf,
                              float* __restrict__ out_idx, bf16_t* __restrict__ xb) {
    const int n = blockIdx.x;
    const int lane = threadIdx.x;  // 64 threads = 1 wave
    const float* xr = x + (size_t)n * C;
    bf16_t* xbr = xb + (size_t)n * C;
    float acc[NE] = {0.f, 0.f, 0.f, 0.f, 0.f, 0.f, 0.f, 0.f};
    #pragma unroll
    for (int i = 0; i < C / 64; i++) {
        int c = i * 64 + lane;
        float xv = xr[c];
        xbr[c] = (bf16_t)xv;
        const float4* w = (const float4*)(Wg + (size_t)c * NE);
        float4 w0 = w[0], w1 = w[1];
        acc[0] += xv * w0.x; acc[1] += xv * w0.y; acc[2] += xv * w0.z; acc[3] += xv * w0.w;
        acc[4] += xv * w1.x; acc[5] += xv * w1.y; acc[6] += xv * w1.z; acc[7] += xv * w1.w;
    }
    #pragma unroll
    for (int off = 32; off >= 1; off >>= 1)
        #pragma unroll
        for (int e = 0; e < NE; e++) acc[e] += __shfl_down(acc[e], off);
    if (lane == 0) {
        float v0 = -1e30f, v1 = -1e30f; int i0 = 0, i1 = 0;
        #pragma unroll
        for (int e = 0; e < NE; e++) {
            float v = acc[e];
            if (v > v0)      { v1 = v0; i1 = i0; v0 = v; i0 = e; }
            else if (v > v1) { v1 = v; i1 = e; }
        }
        float e1 = __expf(v1 - v0);
        probs[n * 2]     = 1.0f / (1.0f + e1);
        probs[n * 2 + 1] = e1 / (1.0f + e1);
        idxbuf[n * 2]     = i0;
        idxbuf[n * 2 + 1] = i1;
        out_idx[n * 2]     = (float)i0;
        out_idx[n * 2 + 1] = (float)i1;
    }
}

// ---------------- group tokens by expert (single block) ----------------
__global__ void group_kernel(const int* __restrict__ idxbuf, int* __restrict__ rowinfo,
                             int* __restrict__ counts, int* __restrict__ offs, int N) {
    __shared__ int cnt[NE], run[NE], base[NE];
    const int t = threadIdx.x;
    if (t < NE) { cnt[t] = 0; run[t] = 0; }
    __syncthreads();
    for (int i = t; i < N * 2; i += blockDim.x) atomicAdd(&cnt[idxbuf[i]], 1);
    __syncthreads();
    if (t == 0) { int s = 0; for (int e = 0; e < NE; e++) { base[e] = s; s += cnt[e]; } }
    __syncthreads();
    for (int i = t; i < N * 2; i += blockDim.x) {
        int e = idxbuf[i];
        int p = atomicAdd(&run[e], 1);
        rowinfo[base[e] + p] = i;          // i = n*2 + k
    }
    if (t < NE) { counts[t] = cnt[t]; offs[t] = base[t]; }
}

// ---------------- convert + transpose weights: fp32 [R][Cc] -> bf16 [Cc][R] ----------------
// Write-coalesced register transpose: lane patch = 4 src-rows x 8 src-cols;
// wave lanes sweep rows -> each store = 64 lanes x 8 B = 512 B contiguous burst.
// Reads are 16 B-granule scattered but every fetched 64 B line is fully used by the block.
__global__ __launch_bounds__(256)
void convert_kernel(const float* __restrict__ W1, const float* __restrict__ W3,
                    const float* __restrict__ W2, bf16_t* __restrict__ Wt1,
                    bf16_t* __restrict__ Wt3, bf16_t* __restrict__ Wt2) {
    const int yy = blockIdx.y;               // 24 = 3 mats x 8 experts
    const int which = yy >> 3, e = yy & 7;
    const float* src; bf16_t* dst; int R, Cc;
    if (which == 0)      { src = W1; dst = Wt1; R = C; Cc = F; }
    else if (which == 1) { src = W3; dst = Wt3; R = C; Cc = F; }
    else                 { src = W2; dst = Wt2; R = F; Cc = C; }
    src += (size_t)e * C * F;
    dst += (size_t)e * C * F;
    const int tilesR = R >> 8;               // tiles of 256 src-rows; 1024->4, 2816->11
    const int tR = blockIdx.x % tilesR, tC = blockIdx.x / tilesR;  // x = 352 both shapes
    const int t = threadIdx.x;
    const int w = t >> 6, l = t & 63;
    const int r0 = tR * 256 + l * 4;         // 4 src-rows per lane, lanes contiguous in R
    const int c0 = tC * 32 + w * 8;          // 8 src-cols per wave

    const float* sp = src + (size_t)r0 * Cc + c0;
    float4 va[4], vb[4];
    #pragma unroll
    for (int i = 0; i < 4; i++) {
        va[i] = *(const float4*)(sp + (size_t)i * Cc);
        vb[i] = *(const float4*)(sp + (size_t)i * Cc + 4);
    }
    uint2 o;
#define ST(j, A, comp)                                             \
    o.x = pk2(A[0].comp, A[1].comp);                               \
    o.y = pk2(A[2].comp, A[3].comp);                               \
    *(uint2*)(dst + (size_t)(c0 + (j)) * R + r0) = o;
    ST(0, va, x) ST(1, va, y) ST(2, va, z) ST(3, va, w)
    ST(4, vb, x) ST(5, vb, y) ST(6, vb, z) ST(7, vb, w)
#undef ST
}

// ---------------- GEMM1: h = silu(Xg@W1) * (Xg@W3), grouped per expert ----------------
__global__ __launch_bounds__(256, 2)
void gemm1_kernel(const bf16_t* __restrict__ xb, const bf16_t* __restrict__ Wt1,
                  const bf16_t* __restrict__ Wt3, const int* __restrict__ rowinfo,
                  const int* __restrict__ counts, const int* __restrict__ offs,
                  bf16_t* __restrict__ hbuf) {
    const int e = blockIdx.z;
    const int cnt = counts[e];
    const int m0 = blockIdx.y << 7;
    if (m0 >= cnt) return;
    const int base = offs[e];
    const int f0 = blockIdx.x << 7;
    const int t = threadIdx.x;
    const int lane = t & 63, w = t >> 6;
    const int lr = lane & 15, quad = lane >> 4;
    const int wm = (w >> 1) << 6, wn = (w & 1) << 6;

    __shared__ __align__(16) bf16_t As[128 * 32];
    __shared__ __align__(16) bf16_t B1s[128 * 32];
    __shared__ __align__(16) bf16_t B3s[128 * 32];

    const int srow = w * 16 + (lane >> 2);   // staging row within 64-row half
    const int skoff = (lane & 3) * 8;        // bf16 elems within 32-k chunk
    const int r0 = min(m0 + srow, cnt - 1);
    const int r1 = min(m0 + 64 + srow, cnt - 1);
    const bf16_t* ag0 = xb + (size_t)(rowinfo[base + r0] >> 1) * C + skoff;
    const bf16_t* ag1 = xb + (size_t)(rowinfo[base + r1] >> 1) * C + skoff;
    const bf16_t* b1g0 = Wt1 + ((size_t)e * F + f0 + srow) * C + skoff;
    const bf16_t* b1g1 = b1g0 + (size_t)64 * C;
    const bf16_t* b3g0 = Wt3 + ((size_t)e * F + f0 + srow) * C + skoff;
    const bf16_t* b3g1 = b3g0 + (size_t)64 * C;
    bf16_t* lA0 = &As[(w * 16) * 32];
    bf16_t* lA1 = &As[(64 + w * 16) * 32];
    bf16_t* lB10 = &B1s[(w * 16) * 32];
    bf16_t* lB11 = &B1s[(64 + w * 16) * 32];
    bf16_t* lB30 = &B3s[(w * 16) * 32];
    bf16_t* lB31 = &B3s[(64 + w * 16) * 32];

    f32x4 acc1[4][4], acc3[4][4];
    const f32x4 zero = {0.f, 0.f, 0.f, 0.f};
    #pragma unroll
    for (int im = 0; im < 4; im++)
        #pragma unroll
        for (int in = 0; in < 4; in++) { acc1[im][in] = zero; acc3[im][in] = zero; }

    for (int kc = 0; kc < C; kc += 32) {
        async_ld16(ag0 + kc, lA0);
        async_ld16(ag1 + kc, lA1);
        async_ld16(b1g0 + kc, lB10);
        async_ld16(b1g1 + kc, lB11);
        async_ld16(b3g0 + kc, lB30);
        async_ld16(b3g1 + kc, lB31);
        __syncthreads();
        bf16x8 af[4], b1f[4], b3f[4];
        #pragma unroll
        for (int im = 0; im < 4; im++)
            af[im] = *(const bf16x8*)(&As[(wm + im * 16 + lr) * 32 + quad * 8]);
        #pragma unroll
        for (int in = 0; in < 4; in++) {
            b1f[in] = *(const bf16x8*)(&B1s[(wn + in * 16 + lr) * 32 + quad * 8]);
            b3f[in] = *(const bf16x8*)(&B3s[(wn + in * 16 + lr) * 32 + quad * 8]);
        }
        #pragma unroll
        for (int im = 0; im < 4; im++)
            #pragma unroll
            for (int in = 0; in < 4; in++) {
                acc1[im][in] = __builtin_amdgcn_mfma_f32_16x16x32_bf16(af[im], b1f[in], acc1[im][in], 0, 0, 0);
                acc3[im][in] = __builtin_amdgcn_mfma_f32_16x16x32_bf16(af[im], b3f[in], acc3[im][in], 0, 0, 0);
            }
        __syncthreads();
    }
    #pragma unroll
    for (int im = 0; im < 4; im++) {
        #pragma unroll
        for (int r = 0; r < 4; r++) {
            const int row = wm + im * 16 + quad * 4 + r;
            const int gi = m0 + row;
            if (gi < cnt) {
                bf16_t* hp = hbuf + (size_t)(base + gi) * F + f0 + wn + lr;
                #pragma unroll
                for (int in = 0; in < 4; in++) {
                    float h1 = acc1[im][in][r], h3 = acc3[im][in][r];
                    float s = h1 / (1.0f + __expf(-h1)) * h3;
                    hp[in * 16] = (bf16_t)s;
                }
            }
        }
    }
}

// ---------------- GEMM2 (split-K): part[ks][slot] = h @ Wt2[e] over K-slice (bf16 partials) ----------------
__global__ __launch_bounds__(256, 2)
void gemm2_kernel(const bf16_t* __restrict__ hbuf, const bf16_t* __restrict__ Wt2,
                  const int* __restrict__ rowinfo, const int* __restrict__ counts,
                  const int* __restrict__ offs, bf16_t* __restrict__ part,
                  int PK, int nslots) {
    const int z = blockIdx.z;
    const int e = z & 7, ks = z >> 3;
    const int cnt = counts[e];
    const int m0 = blockIdx.y << 7;
    if (m0 >= cnt) return;
    const int base = offs[e];
    const int c0 = blockIdx.x << 7;
    const int t = threadIdx.x;
    const int lane = t & 63, w = t >> 6;
    const int lr = lane & 15, quad = lane >> 4;
    const int wm = (w >> 1) << 6, wn = (w & 1) << 6;

    const int klen = F / PK;
    const int kbeg = ks * klen, kend = kbeg + klen;

    __shared__ __align__(16) bf16_t As[128 * 32];
    __shared__ __align__(16) bf16_t Bs[128 * 32];

    const int srow = w * 16 + (lane >> 2);
    const int skoff = (lane & 3) * 8;
    const int r0 = min(m0 + srow, cnt - 1);
    const int r1 = min(m0 + 64 + srow, cnt - 1);
    const bf16_t* ag0 = hbuf + (size_t)(base + r0) * F + skoff;
    const bf16_t* ag1 = hbuf + (size_t)(base + r1) * F + skoff;
    const bf16_t* bg0 = Wt2 + ((size_t)e * C + c0 + srow) * F + skoff;
    const bf16_t* bg1 = bg0 + (size_t)64 * F;
    bf16_t* lA0 = &As[(w * 16) * 32];
    bf16_t* lA1 = &As[(64 + w * 16) * 32];
    bf16_t* lB0 = &Bs[(w * 16) * 32];
    bf16_t* lB1 = &Bs[(64 + w * 16) * 32];

    f32x4 acc[4][4];
    const f32x4 zero = {0.f, 0.f, 0.f, 0.f};
    #pragma unroll
    for (int im = 0; im < 4; im++)
        #pragma unroll
        for (int in = 0; in < 4; in++) acc[im][in] = zero;

    for (int kc = kbeg; kc < kend; kc += 32) {
        async_ld16(ag0 + kc, lA0);
        async_ld16(ag1 + kc, lA1);
        async_ld16(bg0 + kc, lB0);
        async_ld16(bg1 + kc, lB1);
        __syncthreads();
        bf16x8 af[4], bf_[4];
        #pragma unroll
        for (int im = 0; im < 4; im++)
            af[im] = *(const bf16x8*)(&As[(wm + im * 16 + lr) * 32 + quad * 8]);
        #pragma unroll
        for (int in = 0; in < 4; in++)
            bf_[in] = *(const bf16x8*)(&Bs[(wn + in * 16 + lr) * 32 + quad * 8]);
        #pragma unroll
        for (int im = 0; im < 4; im++)
            #pragma unroll
            for (int in = 0; in < 4; in++)
                acc[im][in] = __builtin_amdgcn_mfma_f32_16x16x32_bf16(af[im], bf_[in], acc[im][in], 0, 0, 0);
        __syncthreads();
    }
    #pragma unroll
    for (int im = 0; im < 4; im++) {
        #pragma unroll
        for (int r = 0; r < 4; r++) {
            const int row = wm + im * 16 + quad * 4 + r;
            const int gi = m0 + row;
            if (gi < cnt) {
                const int slot = rowinfo[base + gi];
                bf16_t* cp = part + ((size_t)ks * nslots + slot) * C + c0 + wn + lr;
                #pragma unroll
                for (int in = 0; in < 4; in++) cp[in * 16] = (bf16_t)acc[im][in][r];
            }
        }
    }
}

// ---------------- reduce partials + combine: y = p0*sum(part[.,2n]) + p1*sum(part[.,2n+1]) ----------------
__global__ void reduce_kernel(const bf16_t* __restrict__ part, const float* __restrict__ probs,
                              float* __restrict__ y, int PK, int nslots) {
    const int idx = blockIdx.x * blockDim.x + threadIdx.x;  // 8 elems per thread
    const int n = idx >> 7;           // C/8 = 128 chunks per row
    const int c = (idx & 127) * 8;
    const size_t ksstride = (size_t)nslots * C;
    const bf16_t* b0 = part + ((size_t)n * 2) * C + c;
    float s0[8] = {0, 0, 0, 0, 0, 0, 0, 0}, s1[8] = {0, 0, 0, 0, 0, 0, 0, 0};
    for (int ks = 0; ks < PK; ks++) {
        bf16x8 a = *(const bf16x8*)(b0 + ks * ksstride);
        bf16x8 b = *(const bf16x8*)(b0 + ks * ksstride + C);
        #pragma unroll
        for (int i = 0; i < 8; i++) { s0[i] += (float)a[i]; s1[i] += (float)b[i]; }
    }
    const float p0 = probs[n * 2], p1 = probs[n * 2 + 1];
    float4 o0, o1;
    o0.x = p0 * s0[0] + p1 * s1[0];
    o0.y = p0 * s0[1] + p1 * s1[1];
    o0.z = p0 * s0[2] + p1 * s1[2];
    o0.w = p0 * s0[3] + p1 * s1[3];
    o1.x = p0 * s0[4] + p1 * s1[4];
    o1.y = p0 * s0[5] + p1 * s1[5];
    o1.z = p0 * s0[6] + p1 * s1[6];
    o1.w = p0 * s0[7] + p1 * s1[7];
    *(float4*)(y + (size_t)n * C + c) = o0;
    *(float4*)(y + (size_t)n * C + c + 4) = o1;
}

extern "C" void kernel_launch(void* const* d_in, const int* in_sizes, int n_in,
                              void* d_out, int out_size, void* d_ws, size_t ws_size,
                              hipStream_t stream) {
    const float* x  = (const float*)d_in[0];
    const float* Wg = (const float*)d_in[1];
    const float* W1 = (const float*)d_in[2];
    const float* W3 = (const float*)d_in[3];
    const float* W2 = (const float*)d_in[4];
    const int N = in_sizes[0] / C;       // 2048 tokens
    const int nslots = N * 2;            // 4096

    float* y = (float*)d_out;
    float* out_idx = y + (size_t)N * C;

    char* ws = (char*)d_ws;
    size_t off = 0;
    auto alloc = [&](size_t bytes) { size_t p = off; off = (off + bytes + 255) & ~(size_t)255; return p; };
    float* probs   = (float*)(ws + alloc((size_t)nslots * 4));
    int* idxbuf    = (int*)(ws + alloc((size_t)nslots * 4));
    int* rowinfo   = (int*)(ws + alloc((size_t)nslots * 4));
    int* counts    = (int*)(ws + alloc(64));
    int* offs      = (int*)(ws + alloc(64));
    bf16_t* xb     = (bf16_t*)(ws + alloc((size_t)N * C * 2));
    bf16_t* hbuf   = (bf16_t*)(ws + alloc((size_t)nslots * F * 2));
    bf16_t* Wt1    = (bf16_t*)(ws + alloc((size_t)NE * C * F * 2));
    bf16_t* Wt3    = (bf16_t*)(ws + alloc((size_t)NE * C * F * 2));
    bf16_t* Wt2    = (bf16_t*)(ws + alloc((size_t)NE * C * F * 2));
    const size_t partbytes = (size_t)nslots * C * 2;  // bf16 partials
    int PK = 1;
    if (off + 4 * partbytes + 1024 <= ws_size) PK = 4;
    else if (off + 2 * partbytes + 1024 <= ws_size) PK = 2;
    bf16_t* part = (bf16_t*)(ws + alloc((size_t)PK * partbytes));

    const int mtiles = nslots / 128;     // worst-case m-tiles per expert

    router_kernel<<<N, 64, 0, stream>>>(x, Wg, probs, idxbuf, out_idx, xb);
    group_kernel<<<1, 256, 0, stream>>>(idxbuf, rowinfo, counts, offs, N);
    convert_kernel<<<dim3(352, 24), 256, 0, stream>>>(W1, W3, W2, Wt1, Wt3, Wt2);
    gemm1_kernel<<<dim3(F / 128, mtiles, NE), 256, 0, stream>>>(xb, Wt1, Wt3, rowinfo, counts, offs, hbuf);
    gemm2_kernel<<<dim3(C / 128, mtiles, NE * PK), 256, 0, stream>>>(hbuf, Wt2, rowinfo, counts, offs, part, PK, nslots);
    reduce_kernel<<<(N * C / 8 + 255) / 256, 256, 0, stream>>>(part, probs, y, PK, nslots);
}